// Round 10
// baseline (370.904 us; speedup 1.0000x reference)
//
#include <hip/hip_runtime.h>
#include <hip/hip_bf16.h>
#include <cstdint>
#include <cstddef>

typedef __bf16 bf16;
typedef __bf16 bf16x8 __attribute__((ext_vector_type(8)));
typedef float f32x4 __attribute__((ext_vector_type(4)));

#define MFMA16(a, b, c) __builtin_amdgcn_mfma_f32_16x16x32_bf16(a, b, c, 0, 0, 0)

#define GLOBAL_LOAD_LDS16(gptr, lptr)                                          \
  __builtin_amdgcn_global_load_lds(                                            \
      (const __attribute__((address_space(1))) void*)(gptr),                   \
      (__attribute__((address_space(3))) void*)(lptr), 16, 0, 0)

// ---------------------------------------------------------------------------
// prep v3: blocks 0..4095 = 64x64 vectorized weight transpose+convert;
// blocks 4096..8191 = LayerNorm + residual copy (out = x), which seeds the
// f32 atomic accumulation done by gemm_out (reduce_out kernel deleted).
// ---------------------------------------------------------------------------
__global__ __launch_bounds__(256) void prep(const float* __restrict__ w_in,
                                            const float* __restrict__ w_attn,
                                            const float* __restrict__ w_ff,
                                            bf16* __restrict__ wt_in,
                                            bf16* __restrict__ wtcat,
                                            const float* __restrict__ x,
                                            const float* __restrict__ ln_w,
                                            const float* __restrict__ ln_b,
                                            bf16* __restrict__ xn,
                                            float* __restrict__ out) {
  __shared__ __align__(16) float t[64][65];   // 16.6 KB
  const int tid = threadIdx.x;
  if (blockIdx.x < 4096) {
    int id = blockIdx.x;
    const float* src; bf16* dst;
    int srcN, n0, k0, kcol0;
    size_t LDO;
    bool win;
    if (id < 2816) {
      src = w_in; dst = wt_in; srcN = 11264; LDO = 1024;
      n0 = (id % 176) * 64; k0 = (id / 176) * 64; kcol0 = 0; win = true;
    } else if (id < 3072) {
      id -= 2816; src = w_attn; dst = wtcat; srcN = 1024; LDO = 5120;
      n0 = (id % 16) * 64; k0 = (id / 16) * 64; kcol0 = 0; win = false;
    } else {
      id -= 3072; src = w_ff; dst = wtcat; srcN = 1024; LDO = 5120;
      n0 = (id % 16) * 64; k0 = (id / 16) * 64; kcol0 = 1024; win = false;
    }
    int drow0;
    if (!win || n0 < 3072) {
      drow0 = n0;
    } else if (n0 < 7168) {
      int m = n0 - 3072; drow0 = 3072 + ((m >> 6) << 7);
    } else {
      int m = n0 - 7168; drow0 = 3072 + ((m >> 6) << 7) + 64;
    }
#pragma unroll
    for (int i = 0; i < 16; i++) {
      int k = i * 4 + (tid >> 6), n = tid & 63;
      t[k][n] = src[(size_t)(k0 + k) * srcN + n0 + n];
    }
    __syncthreads();
#pragma unroll
    for (int j = 0; j < 2; j++) {
      int n = j * 32 + (tid >> 3), kc = (tid & 7) * 8;
      bf16x8 o;
#pragma unroll
      for (int u = 0; u < 8; u++) o[u] = (bf16)t[kc + u][n];
      *(bf16x8*)&dst[(size_t)(drow0 + n) * LDO + kcol0 + k0 + kc] = o;
    }
  } else {
    __shared__ float rs[256], rss[256];
    const int row = blockIdx.x - 4096;
    const float* xr = x + (size_t)row * 1024;
    float4 v = *(const float4*)&xr[tid * 4];
    // residual copy: out = x (gemm_out atomically accumulates on top)
    *(float4*)&out[(size_t)row * 1024 + tid * 4] = v;
    float s = v.x + v.y + v.z + v.w;
    float ss = v.x * v.x + v.y * v.y + v.z * v.z + v.w * v.w;
    rs[tid] = s; rss[tid] = ss;
    __syncthreads();
    for (int off = 128; off > 0; off >>= 1) {
      if (tid < off) { rs[tid] += rs[tid + off]; rss[tid] += rss[tid + off]; }
      __syncthreads();
    }
    const float mean = rs[0] * (1.f / 1024.f);
    const float var = rss[0] * (1.f / 1024.f) - mean * mean;
    const float rstd = rsqrtf(var + 1e-5f);
    const float* vp = (const float*)&v;
    for (int i = 0; i < 4; i++) {
      int c = tid * 4 + i;
      xn[(size_t)row * 1024 + c] = (bf16)((vp[i] - mean) * rstd * ln_w[c] + ln_b[c]);
    }
  }
}

// ---------------------------------------------------------------------------
// Flash attention v2 (fixed-max softmax): QBLK=128, 8 waves, 512 threads.
// ---------------------------------------------------------------------------
__global__ __launch_bounds__(512, 4) void flash_attn(const bf16* __restrict__ proj,
                                                     const bf16* __restrict__ vt,
                                                     bf16* __restrict__ hcat) {
  __shared__ __align__(16) char smem[67584];
  bf16* Ks = (bf16*)smem;                  // [128][64] swizzled
  bf16* Vs = (bf16*)(smem + 16384);        // [64][128] swizzled
  bf16* Ps = (bf16*)(smem + 32768);        // [8][16][136]
  const int tid = threadIdx.x;
  const int wave = tid >> 6, lane = tid & 63;
  const int quad = lane >> 4, l16 = lane & 15;
  const int q0 = blockIdx.x * 128;
  const int h = blockIdx.y, b = blockIdx.z;
  constexpr size_t LDP = 3072;
  const bf16* Qb = proj + (size_t)b * 2048 * LDP + h * 64;
  const bf16* Kb = proj + (size_t)b * 2048 * LDP + 1024 + h * 64;
  const bf16* Vt = vt + (size_t)(b * 16 + h) * 64 * 2048;

  const int qrow = q0 + wave * 16 + l16;
  bf16x8 aq0r = *(const bf16x8*)&Qb[(size_t)qrow * LDP + quad * 8];
  bf16x8 aq1r = *(const bf16x8*)&Qb[(size_t)qrow * LDP + 32 + quad * 8];
  bf16x8 aq0, aq1;
#pragma unroll
  for (int i = 0; i < 8; i++) {
    aq0[i] = (bf16)((float)aq0r[i] * 0.125f);
    aq1[i] = (bf16)((float)aq1r[i] * 0.125f);
  }

  f32x4 O[4] = {};
  float plrow[4] = {0.f, 0.f, 0.f, 0.f};  // per-lane partial row-sums

  const int krow_ = wave * 8 + (lane >> 3);          // p*64 preserves &7
  const int kq_ = ((lane & 7) ^ (krow_ & 7)) * 8;
  const int vrow_ = wave * 4 + (lane >> 4);          // p*32 preserves &15
  const int vq_ = ((lane & 15) ^ (vrow_ & 15)) * 8;

  for (int j0 = 0; j0 < 2048; j0 += 128) {
#pragma unroll
    for (int p = 0; p < 2; p++) {
      int kr = p * 64 + krow_;
      GLOBAL_LOAD_LDS16(&Kb[(size_t)(j0 + kr) * LDP + kq_],
                        &Ks[kr * 64 + (lane & 7) * 8]);
      int vr = p * 32 + vrow_;
      GLOBAL_LOAD_LDS16(&Vt[(size_t)vr * 2048 + j0 + vq_],
                        &Vs[vr * 128 + (lane & 15) * 8]);
    }
    __syncthreads();

    f32x4 sa[8];
#pragma unroll
    for (int nt = 0; nt < 8; nt++) {
      int r = nt * 16 + l16;
      bf16x8 bk0 = *(const bf16x8*)&Ks[r * 64 + (quad ^ (r & 7)) * 8];
      bf16x8 bk1 = *(const bf16x8*)&Ks[r * 64 + ((quad + 4) ^ (r & 7)) * 8];
      f32x4 t = {};
      t = MFMA16(aq0, bk0, t);
      sa[nt] = MFMA16(aq1, bk1, t);
    }

    bf16* Pw = Ps + wave * (16 * 136);
#pragma unroll
    for (int r = 0; r < 4; r++) {
      bf16* pr = &Pw[(quad * 4 + r) * 136];
      float ts = 0.f;
#pragma unroll
      for (int nt = 0; nt < 8; nt++) {
        float p = __expf(sa[nt][r]);
        pr[nt * 16 + l16] = (bf16)p;
        ts += p;
      }
      plrow[r] += ts;  // defer cross-lane reduce to epilogue
    }

#pragma unroll
    for (int kg = 0; kg < 4; kg++) {
      bf16x8 aP = *(const bf16x8*)&Pw[l16 * 136 + kg * 32 + quad * 8];
#pragma unroll
      for (int nb = 0; nb < 4; nb++) {
        int vrr = nb * 16 + l16;
        int vsl = ((kg * 4 + quad) ^ (vrr & 15)) * 8;
        bf16x8 bv = *(const bf16x8*)&Vs[vrr * 128 + vsl];
        O[nb] = MFMA16(aP, bv, O[nb]);
      }
    }
    __syncthreads();
  }

#pragma unroll
  for (int r = 0; r < 4; r++) {
    float ts = plrow[r];
#pragma unroll
    for (int d = 1; d < 16; d <<= 1) ts += __shfl_xor(ts, d, 64);
    float inv = 1.f / ts;
    size_t row = (size_t)b * 2048 + q0 + wave * 16 + quad * 4 + r;
#pragma unroll
    for (int nb = 0; nb < 4; nb++)
      hcat[row * 5120 + h * 64 + nb * 16 + l16] = (bf16)(O[nb][r] * inv);
  }
}

// ---------------------------------------------------------------------------
// proj GEMM (R7-proven best): 256x256, BK=32, 3-buffer LDS (96 KB),
// counted-vmcnt depth-2 pipeline, setprio, XCD-rect swizzle.
// Epilogue: Q/K->proj; V->vt transposed; ff|gate gelu->hcat.
// NOTE (R8 lesson): per-thread state ~232 unified regs; launch_bounds
// min-waves > 2 spills catastrophically. Keep (512, 2).
// ---------------------------------------------------------------------------
__global__ __launch_bounds__(512, 2) void gemm_proj(const bf16* __restrict__ A,
                                                    const bf16* __restrict__ Bt,
                                                    bf16* __restrict__ proj,
                                                    bf16* __restrict__ hcat,
                                                    bf16* __restrict__ vt) {
  constexpr int K = 1024, NT = 32;
  __shared__ __align__(16) char smem[98304];   // 3 x (As 16K + Bs 16K)
  const int tid = threadIdx.x;
  const int wave = tid >> 6, lane = tid & 63;
  const int quad = lane >> 4, l16 = lane & 15;
  const int wm0 = (wave >> 2) * 128, wn0 = (wave & 3) * 64;

  // XCD-rect swizzle (bijective: 704 = 8 xcd * 88 slots = (4*11)x * (2*8)y)
  const int id = (int)blockIdx.y * 44 + (int)blockIdx.x;
  const int xcd = id & 7, s = id >> 3;           // s in 0..87
  const int tx = (xcd & 3) * 11 + s % 11;        // 0..43
  const int ty = (xcd >> 2) * 8 + s / 11;        // 0..15

  const size_t rowA0 = (size_t)ty * 256;
  const size_t rowB0 = (size_t)tx * 256;
  const bf16* Ag = A + rowA0 * K;
  const bf16* Bg = Bt + rowB0 * K;

  const int srow = tid >> 2;
  const int sslot = tid & 3;
  const int rslot = (quad ^ ((l16 >> 1) & 3)) * 8;

  f32x4 acc[8][4] = {};

  auto STAGE = [&](int kt, int buf) {
    bf16* As = (bf16*)(smem + buf * 32768);
    bf16* Bs = As + 256 * 32;
    const int k0 = kt * 32;
#pragma unroll
    for (int p = 0; p < 2; p++) {
      int r = p * 128 + srow;
      int kq = (sslot ^ ((r >> 1) & 3)) * 8;
      GLOBAL_LOAD_LDS16(&Ag[(size_t)r * K + k0 + kq], &As[r * 32 + sslot * 8]);
      GLOBAL_LOAD_LDS16(&Bg[(size_t)r * K + k0 + kq], &Bs[r * 32 + sslot * 8]);
    }
  };

  STAGE(0, 0);
  STAGE(1, 1);
  asm volatile("s_waitcnt vmcnt(4)" ::: "memory");  // kt0 landed, kt1 in flight
  __builtin_amdgcn_s_barrier();
  asm volatile("" ::: "memory");

  int cbuf = 0, sbuf = 2;
#pragma unroll 1
  for (int kt = 0; kt < NT; kt++) {
    if (kt + 2 < NT) STAGE(kt + 2, sbuf);
    const bf16* As = (const bf16*)(smem + cbuf * 32768);
    const bf16* Bs = As + 256 * 32;
    bf16x8 bfr[4];
#pragma unroll
    for (int j = 0; j < 4; j++)
      bfr[j] = *(const bf16x8*)&Bs[(wn0 + j * 16 + l16) * 32 + rslot];
#pragma unroll
    for (int ih = 0; ih < 2; ih++) {
      bf16x8 af[4];
#pragma unroll
      for (int i = 0; i < 4; i++)
        af[i] = *(const bf16x8*)&As[(wm0 + (ih * 4 + i) * 16 + l16) * 32 + rslot];
      __builtin_amdgcn_s_setprio(1);
#pragma unroll
      for (int i = 0; i < 4; i++)
#pragma unroll
        for (int j = 0; j < 4; j++)
          acc[ih * 4 + i][j] = MFMA16(af[i], bfr[j], acc[ih * 4 + i][j]);
      __builtin_amdgcn_s_setprio(0);
    }
    if (kt + 2 < NT) {
      asm volatile("s_waitcnt vmcnt(4)" ::: "memory");  // kt+1 landed
    } else {
      asm volatile("s_waitcnt vmcnt(0)" ::: "memory");  // tail drain
    }
    __builtin_amdgcn_s_barrier();
    asm volatile("" ::: "memory");
    cbuf = (cbuf == 2) ? 0 : cbuf + 1;
    sbuf = (sbuf == 2) ? 0 : sbuf + 1;
  }

  // epilogue: two 128-row halves through LDS
  {
    const int xb = tx;
    const int T2 = xb - 12;
    bf16* Cs = (bf16*)smem;          // [128][264]
    constexpr int LDC2 = 264;
#pragma unroll 1
    for (int h = 0; h < 2; h++) {
      if ((wave >> 2) == h) {
#pragma unroll
        for (int i = 0; i < 8; i++)
#pragma unroll
          for (int j = 0; j < 4; j++)
#pragma unroll
            for (int r = 0; r < 4; r++)
              Cs[(i * 16 + quad * 4 + r) * LDC2 + wn0 + j * 16 + l16] =
                  (bf16)acc[i][j][r];
      }
      __syncthreads();
      if (xb < 8) {
        // Q/K tiles -> proj
#pragma unroll
        for (int it = 0; it < 8; it++) {
          int idx = it * 512 + tid;          // 128 rows x 32 chunks
          int row = idx >> 5, ch = (idx & 31) * 8;
          *(bf16x8*)&proj[(rowA0 + h * 128 + row) * 3072 + rowB0 + ch] =
              *(const bf16x8*)&Cs[row * LDC2 + ch];
        }
      } else if (T2 < 0) {
        // V tiles -> vt transposed: vt[(b*16+head)*64+d][s]
        const int g0 = (int)rowA0 + h * 128;   // global row base (b*2048+s)
        const int bb = g0 >> 11, sloc0 = g0 & 2047;
        const int hb = (xb - 8) * 4;           // head base for this tile
        bf16* vtb = vt + ((size_t)(bb * 16 + hb) * 64) * 2048 + sloc0;
#pragma unroll
        for (int it = 0; it < 8; it++) {
          int u = it * 512 + tid;              // 4096 units
          int col = u & 255, sc = u >> 8;      // col = head*64+d, sc = s-chunk
          bf16x8 o;
#pragma unroll
          for (int k = 0; k < 8; k++) o[k] = Cs[(sc * 8 + k) * LDC2 + col];
          *(bf16x8*)&vtb[(size_t)col * 2048 + sc * 8] = o;
        }
      } else {
        // ff|gate gelu -> hcat
#pragma unroll
        for (int it = 0; it < 4; it++) {
          int idx = it * 512 + tid;          // 128 rows x 2 pairs x 8 chunks
          int row = idx >> 4;
          int p = (idx >> 3) & 1, c8 = (idx & 7) * 8;
          bf16x8 f = *(const bf16x8*)&Cs[row * LDC2 + p * 128 + c8];
          bf16x8 g = *(const bf16x8*)&Cs[row * LDC2 + p * 128 + 64 + c8];
          bf16x8 o;
#pragma unroll
          for (int i = 0; i < 8; i++) {
            float xg = (float)g[i];
            float u = 0.7978845608f * (xg + 0.044715f * xg * xg * xg);
            float gl = xg / (1.f + __expf(-2.f * u));
            o[i] = (bf16)((float)f[i] * gl);
          }
          *(bf16x8*)&hcat[(rowA0 + h * 128 + row) * 5120 + 1024 +
                          (2 * T2 + p) * 64 + c8] = o;
        }
      }
      __syncthreads();
    }
  }
}

// ---------------------------------------------------------------------------
// Output GEMM v5: same R7 main loop (256x256, BK=32, 3-buffer counted-vmcnt,
// split-K=4, XCD-rect swizzle); epilogue is now direct f32 atomicAdd into
// out (seeded with x by prep). Deletes bf16 partials + reduce_out kernel;
// f32 accumulation improves precision vs bf16 partials.
// ---------------------------------------------------------------------------
__global__ __launch_bounds__(512, 2) void gemm_out(const bf16* __restrict__ A,
                                                   const bf16* __restrict__ Bt,
                                                   float* __restrict__ out) {
  constexpr int LDAB = 5120, NT = 40;
  __shared__ __align__(16) char smem[98304];   // 3 x (As 16K + Bs 16K)
  const int tid = threadIdx.x;
  const int wave = tid >> 6, lane = tid & 63;
  const int quad = lane >> 4, l16 = lane & 15;
  const int wm0 = (wave >> 2) * 128, wn0 = (wave & 3) * 64;

  // XCD-rect swizzle (bijective: 256 = 8 xcd * 32 slots = 4x * (2*8)y * 4z)
  const int id = (int)blockIdx.z * 64 + (int)blockIdx.y * 4 + (int)blockIdx.x;
  const int xcd = id & 7, s = id >> 3;           // s in 0..31
  const int tz = xcd >> 1;                       // 0..3
  const int tx = s & 3;                          // 0..3
  const int ty = (xcd & 1) * 8 + (s >> 2);       // 0..15

  const size_t rowA0 = (size_t)ty * 256;
  const size_t rowB0 = (size_t)tx * 256;
  const int kbeg = tz * 1280;
  const bf16* Ag = A + rowA0 * LDAB + kbeg;
  const bf16* Bg = Bt + rowB0 * LDAB + kbeg;

  const int srow = tid >> 2;
  const int sslot = tid & 3;
  const int rslot = (quad ^ ((l16 >> 1) & 3)) * 8;

  f32x4 acc[8][4] = {};

  auto STAGE = [&](int kt, int buf) {
    bf16* As = (bf16*)(smem + buf * 32768);
    bf16* Bs = As + 256 * 32;
    const int k0 = kt * 32;
#pragma unroll
    for (int p = 0; p < 2; p++) {
      int r = p * 128 + srow;
      int kq = (sslot ^ ((r >> 1) & 3)) * 8;
      GLOBAL_LOAD_LDS16(&Ag[(size_t)r * LDAB + k0 + kq], &As[r * 32 + sslot * 8]);
      GLOBAL_LOAD_LDS16(&Bg[(size_t)r * LDAB + k0 + kq], &Bs[r * 32 + sslot * 8]);
    }
  };

  STAGE(0, 0);
  STAGE(1, 1);
  asm volatile("s_waitcnt vmcnt(4)" ::: "memory");
  __builtin_amdgcn_s_barrier();
  asm volatile("" ::: "memory");

  int cbuf = 0, sbuf = 2;
#pragma unroll 1
  for (int kt = 0; kt < NT; kt++) {
    if (kt + 2 < NT) STAGE(kt + 2, sbuf);
    const bf16* As = (const bf16*)(smem + cbuf * 32768);
    const bf16* Bs = As + 256 * 32;
    bf16x8 bfr[4];
#pragma unroll
    for (int j = 0; j < 4; j++)
      bfr[j] = *(const bf16x8*)&Bs[(wn0 + j * 16 + l16) * 32 + rslot];
#pragma unroll
    for (int ih = 0; ih < 2; ih++) {
      bf16x8 af[4];
#pragma unroll
      for (int i = 0; i < 4; i++)
        af[i] = *(const bf16x8*)&As[(wm0 + (ih * 4 + i) * 16 + l16) * 32 + rslot];
      __builtin_amdgcn_s_setprio(1);
#pragma unroll
      for (int i = 0; i < 4; i++)
#pragma unroll
        for (int j = 0; j < 4; j++)
          acc[ih * 4 + i][j] = MFMA16(af[i], bfr[j], acc[ih * 4 + i][j]);
      __builtin_amdgcn_s_setprio(0);
    }
    if (kt + 2 < NT) {
      asm volatile("s_waitcnt vmcnt(4)" ::: "memory");
    } else {
      asm volatile("s_waitcnt vmcnt(0)" ::: "memory");
    }
    __builtin_amdgcn_s_barrier();
    asm volatile("" ::: "memory");
    cbuf = (cbuf == 2) ? 0 : cbuf + 1;
    sbuf = (sbuf == 2) ? 0 : sbuf + 1;
  }

  // epilogue: direct f32 atomic accumulation into out (no LDS round-trip)
#pragma unroll
  for (int i = 0; i < 8; i++) {
    size_t row = rowA0 + wm0 + i * 16 + quad * 4;
#pragma unroll
    for (int j = 0; j < 4; j++) {
      size_t col = rowB0 + wn0 + j * 16 + l16;
#pragma unroll
      for (int r = 0; r < 4; r++)
        atomicAdd(&out[(row + r) * 1024 + col], acc[i][j][r]);
    }
  }
}

// ---------------------------------------------------------------------------
extern "C" void kernel_launch(void* const* d_in, const int* in_sizes, int n_in,
                              void* d_out, int out_size, void* d_ws, size_t ws_size,
                              hipStream_t stream) {
  const float* x      = (const float*)d_in[0];
  const float* ln_w   = (const float*)d_in[1];
  const float* ln_b   = (const float*)d_in[2];
  const float* w_in   = (const float*)d_in[3];  // [1024,11264]
  const float* w_attn = (const float*)d_in[4];  // [1024,1024]
  const float* w_ff   = (const float*)d_in[5];  // [4096,1024]
  float* out = (float*)d_out;
  char* ws = (char*)d_ws;

  bf16* wt_in = (bf16*)(ws);                 // [11264][1024] 23068672 B
  bf16* wtcat = (bf16*)(ws + 23068672);      // [1024][5120]  10485760 B
  bf16* xn    = (bf16*)(ws + 33554432);      // [4096][1024]   8388608 B
  bf16* proj  = (bf16*)(ws + 41943040);      // [4096][3072]  25165824 B
  bf16* vt    = (bf16*)(ws + 67108864);      // [32][64][2048]  8388608 B
  bf16* hcat  = (bf16*)(ws + 75497472);      // [4096][5120]  41943040 B

  prep<<<8192, 256, 0, stream>>>(w_in, w_attn, w_ff, wt_in, wtcat,
                                 x, ln_w, ln_b, xn, out);
  gemm_proj<<<dim3(44, 16), 512, 0, stream>>>(xn, wt_in, proj, hcat, vt);
  flash_attn<<<dim3(16, 16, 2), 512, 0, stream>>>(proj, vt, hcat);
  gemm_out<<<dim3(4, 16, 4), 512, 0, stream>>>(hcat, wtcat, out);
}

// Round 11
// 348.722 us; speedup vs baseline: 1.0636x; 1.0636x over previous
//
#include <hip/hip_runtime.h>
#include <hip/hip_bf16.h>
#include <cstdint>
#include <cstddef>

typedef __bf16 bf16;
typedef __bf16 bf16x8 __attribute__((ext_vector_type(8)));
typedef float f32x4 __attribute__((ext_vector_type(4)));

#define MFMA16(a, b, c) __builtin_amdgcn_mfma_f32_16x16x32_bf16(a, b, c, 0, 0, 0)

#define GLOBAL_LOAD_LDS16(gptr, lptr)                                          \
  __builtin_amdgcn_global_load_lds(                                            \
      (const __attribute__((address_space(1))) void*)(gptr),                   \
      (__attribute__((address_space(3))) void*)(lptr), 16, 0, 0)

// ---------------------------------------------------------------------------
// prep v2 (R6-proven): blocks 0..4095 = 64x64 vectorized weight
// transpose+convert; blocks 4096..8191 = LayerNorm.
// ---------------------------------------------------------------------------
__global__ __launch_bounds__(256) void prep(const float* __restrict__ w_in,
                                            const float* __restrict__ w_attn,
                                            const float* __restrict__ w_ff,
                                            bf16* __restrict__ wt_in,
                                            bf16* __restrict__ wtcat,
                                            const float* __restrict__ x,
                                            const float* __restrict__ ln_w,
                                            const float* __restrict__ ln_b,
                                            bf16* __restrict__ xn) {
  __shared__ __align__(16) float t[64][65];   // 16.6 KB
  const int tid = threadIdx.x;
  if (blockIdx.x < 4096) {
    int id = blockIdx.x;
    const float* src; bf16* dst;
    int srcN, n0, k0, kcol0;
    size_t LDO;
    bool win;
    if (id < 2816) {
      src = w_in; dst = wt_in; srcN = 11264; LDO = 1024;
      n0 = (id % 176) * 64; k0 = (id / 176) * 64; kcol0 = 0; win = true;
    } else if (id < 3072) {
      id -= 2816; src = w_attn; dst = wtcat; srcN = 1024; LDO = 5120;
      n0 = (id % 16) * 64; k0 = (id / 16) * 64; kcol0 = 0; win = false;
    } else {
      id -= 3072; src = w_ff; dst = wtcat; srcN = 1024; LDO = 5120;
      n0 = (id % 16) * 64; k0 = (id / 16) * 64; kcol0 = 1024; win = false;
    }
    int drow0;
    if (!win || n0 < 3072) {
      drow0 = n0;
    } else if (n0 < 7168) {
      int m = n0 - 3072; drow0 = 3072 + ((m >> 6) << 7);
    } else {
      int m = n0 - 7168; drow0 = 3072 + ((m >> 6) << 7) + 64;
    }
#pragma unroll
    for (int i = 0; i < 16; i++) {
      int k = i * 4 + (tid >> 6), n = tid & 63;
      t[k][n] = src[(size_t)(k0 + k) * srcN + n0 + n];
    }
    __syncthreads();
#pragma unroll
    for (int j = 0; j < 2; j++) {
      int n = j * 32 + (tid >> 3), kc = (tid & 7) * 8;
      bf16x8 o;
#pragma unroll
      for (int u = 0; u < 8; u++) o[u] = (bf16)t[kc + u][n];
      *(bf16x8*)&dst[(size_t)(drow0 + n) * LDO + kcol0 + k0 + kc] = o;
    }
  } else {
    __shared__ float rs[256], rss[256];
    const int row = blockIdx.x - 4096;
    const float* xr = x + (size_t)row * 1024;
    float4 v = *(const float4*)&xr[tid * 4];
    float s = v.x + v.y + v.z + v.w;
    float ss = v.x * v.x + v.y * v.y + v.z * v.z + v.w * v.w;
    rs[tid] = s; rss[tid] = ss;
    __syncthreads();
    for (int off = 128; off > 0; off >>= 1) {
      if (tid < off) { rs[tid] += rs[tid + off]; rss[tid] += rss[tid + off]; }
      __syncthreads();
    }
    const float mean = rs[0] * (1.f / 1024.f);
    const float var = rss[0] * (1.f / 1024.f) - mean * mean;
    const float rstd = rsqrtf(var + 1e-5f);
    const float* vp = (const float*)&v;
    for (int i = 0; i < 4; i++) {
      int c = tid * 4 + i;
      xn[(size_t)row * 1024 + c] = (bf16)((vp[i] - mean) * rstd * ln_w[c] + ln_b[c]);
    }
  }
}

// ---------------------------------------------------------------------------
// Flash attention v2 (R6-proven): QBLK=128, 8 waves, 512 threads, fixed-max
// softmax, global_load_lds + XOR-swizzled LDS, deferred row-sum reduce.
// ---------------------------------------------------------------------------
__global__ __launch_bounds__(512, 4) void flash_attn(const bf16* __restrict__ proj,
                                                     const bf16* __restrict__ vt,
                                                     bf16* __restrict__ hcat) {
  __shared__ __align__(16) char smem[67584];
  bf16* Ks = (bf16*)smem;                  // [128][64] swizzled
  bf16* Vs = (bf16*)(smem + 16384);        // [64][128] swizzled
  bf16* Ps = (bf16*)(smem + 32768);        // [8][16][136]
  const int tid = threadIdx.x;
  const int wave = tid >> 6, lane = tid & 63;
  const int quad = lane >> 4, l16 = lane & 15;
  const int q0 = blockIdx.x * 128;
  const int h = blockIdx.y, b = blockIdx.z;
  constexpr size_t LDP = 3072;
  const bf16* Qb = proj + (size_t)b * 2048 * LDP + h * 64;
  const bf16* Kb = proj + (size_t)b * 2048 * LDP + 1024 + h * 64;
  const bf16* Vt = vt + (size_t)(b * 16 + h) * 64 * 2048;

  const int qrow = q0 + wave * 16 + l16;
  bf16x8 aq0r = *(const bf16x8*)&Qb[(size_t)qrow * LDP + quad * 8];
  bf16x8 aq1r = *(const bf16x8*)&Qb[(size_t)qrow * LDP + 32 + quad * 8];
  bf16x8 aq0, aq1;
#pragma unroll
  for (int i = 0; i < 8; i++) {
    aq0[i] = (bf16)((float)aq0r[i] * 0.125f);
    aq1[i] = (bf16)((float)aq1r[i] * 0.125f);
  }

  f32x4 O[4] = {};
  float plrow[4] = {0.f, 0.f, 0.f, 0.f};  // per-lane partial row-sums

  const int krow_ = wave * 8 + (lane >> 3);          // p*64 preserves &7
  const int kq_ = ((lane & 7) ^ (krow_ & 7)) * 8;
  const int vrow_ = wave * 4 + (lane >> 4);          // p*32 preserves &15
  const int vq_ = ((lane & 15) ^ (vrow_ & 15)) * 8;

  for (int j0 = 0; j0 < 2048; j0 += 128) {
#pragma unroll
    for (int p = 0; p < 2; p++) {
      int kr = p * 64 + krow_;
      GLOBAL_LOAD_LDS16(&Kb[(size_t)(j0 + kr) * LDP + kq_],
                        &Ks[kr * 64 + (lane & 7) * 8]);
      int vr = p * 32 + vrow_;
      GLOBAL_LOAD_LDS16(&Vt[(size_t)vr * 2048 + j0 + vq_],
                        &Vs[vr * 128 + (lane & 15) * 8]);
    }
    __syncthreads();

    f32x4 sa[8];
#pragma unroll
    for (int nt = 0; nt < 8; nt++) {
      int r = nt * 16 + l16;
      bf16x8 bk0 = *(const bf16x8*)&Ks[r * 64 + (quad ^ (r & 7)) * 8];
      bf16x8 bk1 = *(const bf16x8*)&Ks[r * 64 + ((quad + 4) ^ (r & 7)) * 8];
      f32x4 t = {};
      t = MFMA16(aq0, bk0, t);
      sa[nt] = MFMA16(aq1, bk1, t);
    }

    bf16* Pw = Ps + wave * (16 * 136);
#pragma unroll
    for (int r = 0; r < 4; r++) {
      bf16* pr = &Pw[(quad * 4 + r) * 136];
      float ts = 0.f;
#pragma unroll
      for (int nt = 0; nt < 8; nt++) {
        float p = __expf(sa[nt][r]);
        pr[nt * 16 + l16] = (bf16)p;
        ts += p;
      }
      plrow[r] += ts;  // defer cross-lane reduce to epilogue
    }

#pragma unroll
    for (int kg = 0; kg < 4; kg++) {
      bf16x8 aP = *(const bf16x8*)&Pw[l16 * 136 + kg * 32 + quad * 8];
#pragma unroll
      for (int nb = 0; nb < 4; nb++) {
        int vrr = nb * 16 + l16;
        int vsl = ((kg * 4 + quad) ^ (vrr & 15)) * 8;
        bf16x8 bv = *(const bf16x8*)&Vs[vrr * 128 + vsl];
        O[nb] = MFMA16(aP, bv, O[nb]);
      }
    }
    __syncthreads();
  }

#pragma unroll
  for (int r = 0; r < 4; r++) {
    float ts = plrow[r];
#pragma unroll
    for (int d = 1; d < 16; d <<= 1) ts += __shfl_xor(ts, d, 64);
    float inv = 1.f / ts;
    size_t row = (size_t)b * 2048 + q0 + wave * 16 + quad * 4 + r;
#pragma unroll
    for (int nb = 0; nb < 4; nb++)
      hcat[row * 5120 + h * 64 + nb * 16 + l16] = (bf16)(O[nb][r] * inv);
  }
}

// ---------------------------------------------------------------------------
// proj GEMM (R3/R6-proven best): 256x256, BK=32, 3-buffer LDS (96 KB),
// counted-vmcnt depth-2 pipeline, setprio around MFMA cluster.
// Epilogue split: x<8 -> Q/K -> proj; x in [8,12) -> V transposed -> vt;
// x>=12 -> ff|gate gelu -> hcat.
// R8 lesson: per-thread state ~232 unified regs (128 AGPR acc + 104 VGPR);
// launch_bounds min-waves > 2 spills catastrophically. Keep (512, 2).
// ---------------------------------------------------------------------------
__global__ __launch_bounds__(512, 2) void gemm_proj(const bf16* __restrict__ A,
                                                    const bf16* __restrict__ Bt,
                                                    bf16* __restrict__ proj,
                                                    bf16* __restrict__ hcat,
                                                    bf16* __restrict__ vt) {
  constexpr int K = 1024, NT = 32;
  __shared__ __align__(16) char smem[98304];   // 3 x (As 16K + Bs 16K)
  const int tid = threadIdx.x;
  const int wave = tid >> 6, lane = tid & 63;
  const int quad = lane >> 4, l16 = lane & 15;
  const int wm0 = (wave >> 2) * 128, wn0 = (wave & 3) * 64;
  const size_t rowA0 = (size_t)blockIdx.y * 256;
  const size_t rowB0 = (size_t)blockIdx.x * 256;
  const bf16* Ag = A + rowA0 * K;
  const bf16* Bg = Bt + rowB0 * K;

  const int srow = tid >> 2;
  const int sslot = tid & 3;
  const int rslot = (quad ^ ((l16 >> 1) & 3)) * 8;

  f32x4 acc[8][4] = {};

  auto STAGE = [&](int kt, int buf) {
    bf16* As = (bf16*)(smem + buf * 32768);
    bf16* Bs = As + 256 * 32;
    const int k0 = kt * 32;
#pragma unroll
    for (int p = 0; p < 2; p++) {
      int r = p * 128 + srow;
      int kq = (sslot ^ ((r >> 1) & 3)) * 8;
      GLOBAL_LOAD_LDS16(&Ag[(size_t)r * K + k0 + kq], &As[r * 32 + sslot * 8]);
      GLOBAL_LOAD_LDS16(&Bg[(size_t)r * K + k0 + kq], &Bs[r * 32 + sslot * 8]);
    }
  };

  STAGE(0, 0);
  STAGE(1, 1);
  asm volatile("s_waitcnt vmcnt(4)" ::: "memory");  // kt0 landed, kt1 in flight
  __builtin_amdgcn_s_barrier();
  asm volatile("" ::: "memory");

  int cbuf = 0, sbuf = 2;
#pragma unroll 1
  for (int kt = 0; kt < NT; kt++) {
    if (kt + 2 < NT) STAGE(kt + 2, sbuf);
    const bf16* As = (const bf16*)(smem + cbuf * 32768);
    const bf16* Bs = As + 256 * 32;
    bf16x8 bfr[4];
#pragma unroll
    for (int j = 0; j < 4; j++)
      bfr[j] = *(const bf16x8*)&Bs[(wn0 + j * 16 + l16) * 32 + rslot];
#pragma unroll
    for (int ih = 0; ih < 2; ih++) {
      bf16x8 af[4];
#pragma unroll
      for (int i = 0; i < 4; i++)
        af[i] = *(const bf16x8*)&As[(wm0 + (ih * 4 + i) * 16 + l16) * 32 + rslot];
      __builtin_amdgcn_s_setprio(1);
#pragma unroll
      for (int i = 0; i < 4; i++)
#pragma unroll
        for (int j = 0; j < 4; j++)
          acc[ih * 4 + i][j] = MFMA16(af[i], bfr[j], acc[ih * 4 + i][j]);
      __builtin_amdgcn_s_setprio(0);
    }
    if (kt + 2 < NT) {
      asm volatile("s_waitcnt vmcnt(4)" ::: "memory");  // kt+1 landed
    } else {
      asm volatile("s_waitcnt vmcnt(0)" ::: "memory");  // tail drain
    }
    __builtin_amdgcn_s_barrier();
    asm volatile("" ::: "memory");
    cbuf = (cbuf == 2) ? 0 : cbuf + 1;
    sbuf = (sbuf == 2) ? 0 : sbuf + 1;
  }

  // epilogue: two 128-row halves through LDS
  {
    const int xb = (int)blockIdx.x;
    const int T2 = xb - 12;
    bf16* Cs = (bf16*)smem;          // [128][264]
    constexpr int LDC2 = 264;
#pragma unroll 1
    for (int h = 0; h < 2; h++) {
      if ((wave >> 2) == h) {
#pragma unroll
        for (int i = 0; i < 8; i++)
#pragma unroll
          for (int j = 0; j < 4; j++)
#pragma unroll
            for (int r = 0; r < 4; r++)
              Cs[(i * 16 + quad * 4 + r) * LDC2 + wn0 + j * 16 + l16] =
                  (bf16)acc[i][j][r];
      }
      __syncthreads();
      if (xb < 8) {
        // Q/K tiles -> proj
#pragma unroll
        for (int it = 0; it < 8; it++) {
          int idx = it * 512 + tid;          // 128 rows x 32 chunks
          int row = idx >> 5, ch = (idx & 31) * 8;
          *(bf16x8*)&proj[(rowA0 + h * 128 + row) * 3072 + rowB0 + ch] =
              *(const bf16x8*)&Cs[row * LDC2 + ch];
        }
      } else if (T2 < 0) {
        // V tiles -> vt transposed: vt[(b*16+head)*64+d][s]
        const int g0 = (int)rowA0 + h * 128;   // global row base (b*2048+s)
        const int bb = g0 >> 11, sloc0 = g0 & 2047;
        const int hb = (xb - 8) * 4;           // head base for this tile
        bf16* vtb = vt + ((size_t)(bb * 16 + hb) * 64) * 2048 + sloc0;
#pragma unroll
        for (int it = 0; it < 8; it++) {
          int u = it * 512 + tid;              // 4096 units
          int col = u & 255, sc = u >> 8;      // col = head*64+d, sc = s-chunk
          bf16x8 o;
#pragma unroll
          for (int k = 0; k < 8; k++) o[k] = Cs[(sc * 8 + k) * LDC2 + col];
          *(bf16x8*)&vtb[(size_t)col * 2048 + sc * 8] = o;
        }
      } else {
        // ff|gate gelu -> hcat
#pragma unroll
        for (int it = 0; it < 4; it++) {
          int idx = it * 512 + tid;          // 128 rows x 2 pairs x 8 chunks
          int row = idx >> 4;
          int p = (idx >> 3) & 1, c8 = (idx & 7) * 8;
          bf16x8 f = *(const bf16x8*)&Cs[row * LDC2 + p * 128 + c8];
          bf16x8 g = *(const bf16x8*)&Cs[row * LDC2 + p * 128 + 64 + c8];
          bf16x8 o;
#pragma unroll
          for (int i = 0; i < 8; i++) {
            float xg = (float)g[i];
            float u = 0.7978845608f * (xg + 0.044715f * xg * xg * xg);
            float gl = xg / (1.f + __expf(-2.f * u));
            o[i] = (bf16)((float)f[i] * gl);
          }
          *(bf16x8*)&hcat[(rowA0 + h * 128 + row) * 5120 + 1024 +
                          (2 * T2 + p) * 64 + c8] = o;
        }
      }
      __syncthreads();
    }
  }
}

// ---------------------------------------------------------------------------
// Output GEMM (R5/R6-proven): 256x256 tile, BK=32, 3-buffer counted-vmcnt,
// 8 waves, split-K=4 -> grid dim3(4,16,4) = 256 blocks = 1/CU, zero tail.
// ---------------------------------------------------------------------------
__global__ __launch_bounds__(512, 2) void gemm_out(const bf16* __restrict__ A,
                                                   const bf16* __restrict__ Bt,
                                                   bf16* __restrict__ part) {
  constexpr int LDAB = 5120, NT = 40;
  __shared__ __align__(16) char smem[98304];   // 3 x (As 16K + Bs 16K)
  const int tid = threadIdx.x;
  const int wave = tid >> 6, lane = tid & 63;
  const int quad = lane >> 4, l16 = lane & 15;
  const int wm0 = (wave >> 2) * 128, wn0 = (wave & 3) * 64;
  const size_t rowA0 = (size_t)blockIdx.y * 256;
  const size_t rowB0 = (size_t)blockIdx.x * 256;
  const int kbeg = blockIdx.z * 1280;
  const bf16* Ag = A + rowA0 * LDAB + kbeg;
  const bf16* Bg = Bt + rowB0 * LDAB + kbeg;

  const int srow = tid >> 2;
  const int sslot = tid & 3;
  const int rslot = (quad ^ ((l16 >> 1) & 3)) * 8;

  f32x4 acc[8][4] = {};

  auto STAGE = [&](int kt, int buf) {
    bf16* As = (bf16*)(smem + buf * 32768);
    bf16* Bs = As + 256 * 32;
    const int k0 = kt * 32;
#pragma unroll
    for (int p = 0; p < 2; p++) {
      int r = p * 128 + srow;
      int kq = (sslot ^ ((r >> 1) & 3)) * 8;
      GLOBAL_LOAD_LDS16(&Ag[(size_t)r * LDAB + k0 + kq], &As[r * 32 + sslot * 8]);
      GLOBAL_LOAD_LDS16(&Bg[(size_t)r * LDAB + k0 + kq], &Bs[r * 32 + sslot * 8]);
    }
  };

  STAGE(0, 0);
  STAGE(1, 1);
  asm volatile("s_waitcnt vmcnt(4)" ::: "memory");
  __builtin_amdgcn_s_barrier();
  asm volatile("" ::: "memory");

  int cbuf = 0, sbuf = 2;
#pragma unroll 1
  for (int kt = 0; kt < NT; kt++) {
    if (kt + 2 < NT) STAGE(kt + 2, sbuf);
    const bf16* As = (const bf16*)(smem + cbuf * 32768);
    const bf16* Bs = As + 256 * 32;
    bf16x8 bfr[4];
#pragma unroll
    for (int j = 0; j < 4; j++)
      bfr[j] = *(const bf16x8*)&Bs[(wn0 + j * 16 + l16) * 32 + rslot];
#pragma unroll
    for (int ih = 0; ih < 2; ih++) {
      bf16x8 af[4];
#pragma unroll
      for (int i = 0; i < 4; i++)
        af[i] = *(const bf16x8*)&As[(wm0 + (ih * 4 + i) * 16 + l16) * 32 + rslot];
      __builtin_amdgcn_s_setprio(1);
#pragma unroll
      for (int i = 0; i < 4; i++)
#pragma unroll
        for (int j = 0; j < 4; j++)
          acc[ih * 4 + i][j] = MFMA16(af[i], bfr[j], acc[ih * 4 + i][j]);
      __builtin_amdgcn_s_setprio(0);
    }
    if (kt + 2 < NT) {
      asm volatile("s_waitcnt vmcnt(4)" ::: "memory");
    } else {
      asm volatile("s_waitcnt vmcnt(0)" ::: "memory");
    }
    __builtin_amdgcn_s_barrier();
    asm volatile("" ::: "memory");
    cbuf = (cbuf == 2) ? 0 : cbuf + 1;
    sbuf = (sbuf == 2) ? 0 : sbuf + 1;
  }

  // epilogue: two 128-row halves through LDS -> part[z]
  {
    bf16* dst = part + (size_t)blockIdx.z * (4096 * 1024);
    bf16* Cs = (bf16*)smem;          // [128][264]
    constexpr int LDC2 = 264;
#pragma unroll 1
    for (int h = 0; h < 2; h++) {
      if ((wave >> 2) == h) {
#pragma unroll
        for (int i = 0; i < 8; i++)
#pragma unroll
          for (int j = 0; j < 4; j++)
#pragma unroll
            for (int r = 0; r < 4; r++)
              Cs[(i * 16 + quad * 4 + r) * LDC2 + wn0 + j * 16 + l16] =
                  (bf16)acc[i][j][r];
      }
      __syncthreads();
#pragma unroll
      for (int it = 0; it < 8; it++) {
        int idx = it * 512 + tid;          // 128 rows x 32 chunks
        int row = idx >> 5, ch = (idx & 31) * 8;
        *(bf16x8*)&dst[(rowA0 + h * 128 + row) * 1024 + rowB0 + ch] =
            *(const bf16x8*)&Cs[row * LDC2 + ch];
      }
      __syncthreads();
    }
  }
}

// ---------------------------------------------------------------------------
// out = x + sum of 4 bf16 partials
// ---------------------------------------------------------------------------
__global__ __launch_bounds__(256) void reduce_out(const float* __restrict__ x,
                                                  const bf16* __restrict__ part,
                                                  float* __restrict__ out) {
  const size_t i = ((size_t)blockIdx.x * 256 + threadIdx.x) * 8;
  constexpr size_t SL = 4096 * 1024;
  float r[8];
  float4 x0 = *(const float4*)&x[i];
  float4 x1 = *(const float4*)&x[i + 4];
  r[0] = x0.x; r[1] = x0.y; r[2] = x0.z; r[3] = x0.w;
  r[4] = x1.x; r[5] = x1.y; r[6] = x1.z; r[7] = x1.w;
#pragma unroll
  for (int z = 0; z < 4; z++) {
    bf16x8 p = *(const bf16x8*)&part[z * SL + i];
#pragma unroll
    for (int k = 0; k < 8; k++) r[k] += (float)p[k];
  }
  float4 o0 = {r[0], r[1], r[2], r[3]};
  float4 o1 = {r[4], r[5], r[6], r[7]};
  *(float4*)&out[i] = o0;
  *(float4*)&out[i + 4] = o1;
}

// ---------------------------------------------------------------------------
extern "C" void kernel_launch(void* const* d_in, const int* in_sizes, int n_in,
                              void* d_out, int out_size, void* d_ws, size_t ws_size,
                              hipStream_t stream) {
  const float* x      = (const float*)d_in[0];
  const float* ln_w   = (const float*)d_in[1];
  const float* ln_b   = (const float*)d_in[2];
  const float* w_in   = (const float*)d_in[3];  // [1024,11264]
  const float* w_attn = (const float*)d_in[4];  // [1024,1024]
  const float* w_ff   = (const float*)d_in[5];  // [4096,1024]
  float* out = (float*)d_out;
  char* ws = (char*)d_ws;

  bf16* wt_in = (bf16*)(ws);                 // [11264][1024] 23068672 B
  bf16* wtcat = (bf16*)(ws + 23068672);      // [1024][5120]  10485760 B
  bf16* xn    = (bf16*)(ws + 33554432);      // [4096][1024]   8388608 B
  bf16* proj  = (bf16*)(ws + 41943040);      // [4096][3072]  25165824 B
  bf16* part  = (bf16*)(ws + 67108864);      // 4x[4096][1024] 33554432 B
  bf16* vt    = (bf16*)(ws + 100663296);     // [32][64][2048]  8388608 B
  bf16* hcat  = (bf16*)(ws + 134217728);     // [4096][5120]  41943040 B

  prep<<<8192, 256, 0, stream>>>(w_in, w_attn, w_ff, wt_in, wtcat,
                                 x, ln_w, ln_b, xn);
  gemm_proj<<<dim3(44, 16), 512, 0, stream>>>(xn, wt_in, proj, hcat, vt);
  flash_attn<<<dim3(16, 16, 2), 512, 0, stream>>>(proj, vt, hcat);
  gemm_out<<<dim3(4, 16, 4), 512, 0, stream>>>(hcat, wtcat, part);
  reduce_out<<<2048, 256, 0, stream>>>(x, part, out);
}